// Round 1
// baseline (336.540 us; speedup 1.0000x reference)
//
#include <hip/hip_runtime.h>

// OutputNeuron scan: per-(b,n) element, fully independent recurrence over T.
//   syn = 0.9*syn + x_t ; mem = 0.95*mem + syn ; s = (mem>1) ; count += s ;
//   mem *= (1-s)
// Memory-bound: must stream 268 MB of x exactly once (~44 us floor at 6.3 TB/s).
// One thread per float4 column. 8-deep rotating prefetch with NAMED registers
// b0..b7 (no array => no runtime indexing => no scratch spill / v_movrel; every
// buffer access is a plain VGPR). The steady loop keeps ~8 global_load_dwordx4
// in flight per wave (compiler waits at vmcnt(7), never vmcnt(0)); at 8 waves/CU
// that is 64 KB outstanding per CU, tolerating >5000-cycle loaded HBM latency
// at full bandwidth. Nontemporal loads: x has zero reuse, don't pollute L2/L3.
//
// Note: __builtin_nontemporal_load requires a native vector type, not HIP's
// HIP_vector_type struct -> use ext_vector_type(4) float for the x stream.

typedef float vfloat4 __attribute__((ext_vector_type(4)));

#define NEURON_ALPHA 0.9f
#define NEURON_BETA  0.95f

#define NEURON_STEP(c)                                   \
    do {                                                 \
        syn[c] = NEURON_ALPHA * syn[c] + xt[c];          \
        mem[c] = NEURON_BETA  * mem[c] + syn[c];         \
        bool sp = (mem[c] > 1.0f);                       \
        cnt[c] += sp ? 1.0f : 0.0f;                      \
        mem[c]  = sp ? 0.0f : mem[c];                    \
    } while (0)

#define NEURON_STEP4()                                   \
    do {                                                 \
        NEURON_STEP(0);                                  \
        NEURON_STEP(1);                                  \
        NEURON_STEP(2);                                  \
        NEURON_STEP(3);                                  \
    } while (0)

// Consume buffer bk (timestep i+k), immediately issue its replacement load
// (timestep i+k+8). All register names are compile-time — pure VGPR rotation.
#define PIPE_STAGE(k, bk)                                             \
    do {                                                              \
        vfloat4 xt = bk;                                              \
        bk = __builtin_nontemporal_load(xp + (size_t)(k) * s4);       \
        NEURON_STEP4();                                               \
    } while (0)

#define DRAIN_STAGE(bk)                                               \
    do {                                                              \
        vfloat4 xt = bk;                                              \
        NEURON_STEP4();                                               \
    } while (0)

__global__ __launch_bounds__(256) void outneuron_scan_kernel(
    const float* __restrict__ x,
    const float* __restrict__ mem0,
    const float* __restrict__ syn0,
    const float* __restrict__ count0,
    float* __restrict__ out,
    int BN, int T)
{
    const int i4  = blockIdx.x * blockDim.x + threadIdx.x; // float4 column index
    const int idx = i4 << 2;
    if (idx >= BN) return;

    vfloat4 syn = *reinterpret_cast<const vfloat4*>(syn0   + idx);
    vfloat4 mem = *reinterpret_cast<const vfloat4*>(mem0   + idx);
    vfloat4 cnt = *reinterpret_cast<const vfloat4*>(count0 + idx);

    const vfloat4* xp = reinterpret_cast<const vfloat4*>(x) + i4;
    const size_t s4 = (size_t)(BN >> 2); // vfloat4 stride between timesteps

    if (T < 8) {
        // Generic small-T fallback (never taken for the harness shape T=128).
        for (int t = 0; t < T; ++t) {
            vfloat4 xt = __builtin_nontemporal_load(xp);
            xp += s4;
            NEURON_STEP4();
        }
        *reinterpret_cast<vfloat4*>(out + idx) = cnt;
        return;
    }

    // Prologue: fill the 8-deep pipeline (T >= 8 guaranteed here).
    vfloat4 b0 = __builtin_nontemporal_load(xp + (size_t)0 * s4);
    vfloat4 b1 = __builtin_nontemporal_load(xp + (size_t)1 * s4);
    vfloat4 b2 = __builtin_nontemporal_load(xp + (size_t)2 * s4);
    vfloat4 b3 = __builtin_nontemporal_load(xp + (size_t)3 * s4);
    vfloat4 b4 = __builtin_nontemporal_load(xp + (size_t)4 * s4);
    vfloat4 b5 = __builtin_nontemporal_load(xp + (size_t)5 * s4);
    vfloat4 b6 = __builtin_nontemporal_load(xp + (size_t)6 * s4);
    vfloat4 b7 = __builtin_nontemporal_load(xp + (size_t)7 * s4);
    xp += (size_t)8 * s4;

    // Steady state: chunks of 8 timesteps. Consume the load from 8 iterations
    // ago; issue the replacement immediately. The reload at stage k targets
    // timestep i+8+k, in range because the loop guard guarantees i+16 <= T.
    int i = 0;
    for (; i + 16 <= T; i += 8) {
        PIPE_STAGE(0, b0);
        PIPE_STAGE(1, b1);
        PIPE_STAGE(2, b2);
        PIPE_STAGE(3, b3);
        PIPE_STAGE(4, b4);
        PIPE_STAGE(5, b5);
        PIPE_STAGE(6, b6);
        PIPE_STAGE(7, b7);
        xp += (size_t)8 * s4;
    }

    // Drain the 8 buffered timesteps i..i+7 (always valid: T - i >= 8 here).
    DRAIN_STAGE(b0);
    DRAIN_STAGE(b1);
    DRAIN_STAGE(b2);
    DRAIN_STAGE(b3);
    DRAIN_STAGE(b4);
    DRAIN_STAGE(b5);
    DRAIN_STAGE(b6);
    DRAIN_STAGE(b7);
    i += 8;

    // Generic tail for T % 8 != 0 (empty for T=128): load-and-consume directly.
    for (; i < T; ++i) {
        vfloat4 xt = __builtin_nontemporal_load(xp);
        xp += s4;
        NEURON_STEP4();
    }

    *reinterpret_cast<vfloat4*>(out + idx) = cnt;
}

extern "C" void kernel_launch(void* const* d_in, const int* in_sizes, int n_in,
                              void* d_out, int out_size, void* d_ws, size_t ws_size,
                              hipStream_t stream) {
    const float* x      = (const float*)d_in[0];
    const float* mem0   = (const float*)d_in[1];
    const float* syn0   = (const float*)d_in[2];
    const float* count0 = (const float*)d_in[3];
    float* out = (float*)d_out;

    const int BN = in_sizes[1];          // B*N = 524288 (divisible by 4)
    const int T  = in_sizes[0] / BN;     // 128

    const int n_threads = BN >> 2;       // one thread per float4
    dim3 block(256);
    dim3 grid((n_threads + block.x - 1) / block.x);
    outneuron_scan_kernel<<<grid, block, 0, stream>>>(x, mem0, syn0, count0, out, BN, T);
}